// Round 5
// baseline (385.001 us; speedup 1.0000x reference)
//
#include <hip/hip_runtime.h>
#include <hip/hip_bf16.h>

#define NN 50000
#define EE 800000
#define SCAN_B 2048
#define NB ((NN + SCAN_B - 1) / SCAN_B)   // 25 scan blocks
#define LOG2E 1.44269504088896340736f

// NOTE: harness materializes integer inputs as int32 -> edge_index is const int*.
// NOTE (r7): fp32 scatter atomics = ~80us atomic-latency wall. Avoided.
// NOTE (r9): CSR holds real edges only; self-loop handled inline in agg kernels.
// NOTE (r10/r11): agg1-over-h1 pins at 77us -> not bytes, concurrency.
// NOTE (r12): aggregate x then project: FETCH 253->139MB, VALU-bound 76%.
// NOTE (r13): pk-math+exp2 only 82->78us: per-SIMD VALU util ~30% -> LATENCY
//             bound (Little's law: ~40 lines/CU in flight = 2.5 TB/s).
// NOTE (r14): slot-ring prefetch (1 trip ahead) decouples dependent gather;
//             per-edge layer1 exps precomputed in scatter (e1[p] float4, aliases
//             h2_bf) -> agg1x body = unpack+16 fma; 4-deep stages both aggs.

typedef short bf16x8 __attribute__((ext_vector_type(8)));
typedef float f32x4  __attribute__((ext_vector_type(4)));
typedef float f32x2  __attribute__((ext_vector_type(2)));

__device__ __forceinline__ float bf2f(unsigned short u) {
    return __uint_as_float(((unsigned)u) << 16);
}
__device__ __forceinline__ unsigned short f2bf(float f) {
    unsigned b = __float_as_uint(f);
    b += 0x7fffu + ((b >> 16) & 1u);           // RNE
    return (unsigned short)(b >> 16);
}
__device__ __forceinline__ float2 bfpair(unsigned u) {
    return make_float2(__uint_as_float(u << 16), __uint_as_float(u & 0xffff0000u));
}
__device__ __forceinline__ f32x2 bfpair2(unsigned u) {
    f32x2 r;
    r.x = __uint_as_float(u << 16);
    r.y = __uint_as_float(u & 0xffff0000u);
    return r;
}

// ---------------- fused prep: v-proj + Asd + Wt casts + hist/rank + x cast ----
// v and Asd are pre-scaled by log2e: alphas live in exp2 domain downstream.
__global__ void k_prep(const float* __restrict__ We1, const float* __restrict__ ae1,
                       const float* __restrict__ We2, const float* __restrict__ ae2,
                       float* __restrict__ v,
                       const float* __restrict__ as1, const float* __restrict__ ad1,
                       float* __restrict__ Asd,
                       const float* __restrict__ W1, unsigned short* __restrict__ W1t,
                       const float* __restrict__ W2, unsigned short* __restrict__ W2t,
                       const int* __restrict__ ei, int* __restrict__ idg,
                       int* __restrict__ rank,
                       const float* __restrict__ x, unsigned short* __restrict__ xb) {
    int bid = blockIdx.x, t = threadIdx.x;
    if (bid == 0) {
        if (t < 8) {            // layer1: c=t>>2, h=t&3 -> v[c*4+h]
            int c = t >> 2, h = t & 3;
            float s = 0.f;
            for (int d = 0; d < 64; d++) s += We1[c * 256 + h * 64 + d] * ae1[h * 64 + d];
            v[c * 4 + h] = s * LOG2E;
        } else if (t < 10) {    // layer2: c=t-8 -> v[8+c]
            int c = t - 8;
            float s = 0.f;
            for (int d = 0; d < 128; d++) s += We2[c * 128 + d] * ae2[d];
            v[8 + c] = s * LOG2E;
        }
        // Asd[k*8+j]: j<4 -> sum_c W1[k,j*64+c]*as1[j,c]; j>=4 -> same with ad1
        #pragma unroll 1
        for (int idx = t; idx < 1024; idx += 256) {
            int k = idx >> 3, j = idx & 7;
            const float* a = (j < 4) ? as1 : ad1;
            int h = j & 3;
            float s = 0.f;
            for (int c = 0; c < 64; c++) s += W1[k * 256 + h * 64 + c] * a[h * 64 + c];
            Asd[idx] = s * LOG2E;
        }
    } else if (bid <= 256) {
        int idx = (bid - 1) * 256 + t;
        if (idx < 32768) {                 // W1: 128x256 -> 256x128
            int k = idx >> 8, n = idx & 255;
            W1t[n * 128 + k] = f2bf(W1[idx]);
        } else {                           // W2: 256x128 -> 128x256
            int i = idx - 32768;
            int k = i >> 7, n = i & 127;
            W2t[n * 256 + k] = f2bf(W2[i]);
        }
    } else if (bid <= 256 + 3125) {
        int e = (bid - 257) * 256 + t;
        if (e < EE) rank[e] = atomicAdd(&idg[ei[EE + e]], 1);
    } else {
        int i = (bid - 3382) * 256 + t;
        if (i < NN * 128 / 4) {
            float4 vv = ((const float4*)x)[i];
            ushort4 o;
            o.x = f2bf(vv.x); o.y = f2bf(vv.y); o.z = f2bf(vv.z); o.w = f2bf(vv.w);
            ((ushort4*)xb)[i] = o;
        }
    }
}

// ---------------- CSR build: 3-pass exclusive scan of idg -> rowptr -----------
__global__ void k_scan1(const int* __restrict__ idg, int* __restrict__ rowptr,
                        int* __restrict__ bsum) {
    __shared__ int sh[512];
    int t = threadIdx.x;
    int base = blockIdx.x * SCAN_B + t * 4;
    int v[4]; int s = 0;
    #pragma unroll
    for (int j = 0; j < 4; j++) {
        int i = base + j;
        v[j] = (i < NN) ? idg[i] : 0;
        s += v[j];
    }
    sh[t] = s;
    __syncthreads();
    for (int off = 1; off < 512; off <<= 1) {
        int a = (t >= off) ? sh[t - off] : 0;
        __syncthreads();
        sh[t] += a;
        __syncthreads();
    }
    int run = sh[t] - s;
    #pragma unroll
    for (int j = 0; j < 4; j++) {
        int i = base + j;
        if (i < NN) rowptr[i] = run;
        run += v[j];
    }
    if (t == 511) bsum[blockIdx.x] = sh[511];
}

__global__ void k_scan2(const int* __restrict__ bsum, int* __restrict__ boff,
                        int* __restrict__ rowptr) {
    if (threadIdx.x == 0) {
        int acc = 0;
        for (int b = 0; b < NB; b++) { boff[b] = acc; acc += bsum[b]; }
        rowptr[NN] = acc;      // == EE
    }
}

__global__ void k_scan3(int* __restrict__ rowptr, const int* __restrict__ boff) {
    int t = threadIdx.x;
    int i = blockIdx.x * SCAN_B + t * 4;
    int off = boff[blockIdx.x];
    #pragma unroll
    for (int j = 0; j < 4; j++)
        if (i + j < NN) rowptr[i + j] += off;
}

// ---------------- layer1 attn scalars: asrc/adst = x . Asd (factored) ---------
// (runs BEFORE scatter now: scatter consumes asrc1/adst1 to precompute e1)
__global__ __launch_bounds__(256) void k_attn1(const unsigned short* __restrict__ xb,
                       const float* __restrict__ Asd,
                       float* __restrict__ asrc, float* __restrict__ adst) {
    int node = blockIdx.x * 4 + (threadIdx.x >> 6);
    if (node >= NN) return;
    int lane = threadIdx.x & 63;
    unsigned xw = *(const unsigned*)(xb + (size_t)node * 128 + lane * 2);
    float2 xc = bfpair(xw);
    const float4* A4 = (const float4*)Asd;     // [k][8] -> float4 pairs
    float4 s0 = A4[lane * 4 + 0];              // k=2l  src
    float4 d0 = A4[lane * 4 + 1];              // k=2l  dst
    float4 s1 = A4[lane * 4 + 2];              // k=2l+1 src
    float4 d1 = A4[lane * 4 + 3];              // k=2l+1 dst
    float r[8];
    r[0] = xc.x * s0.x + xc.y * s1.x;
    r[1] = xc.x * s0.y + xc.y * s1.y;
    r[2] = xc.x * s0.z + xc.y * s1.z;
    r[3] = xc.x * s0.w + xc.y * s1.w;
    r[4] = xc.x * d0.x + xc.y * d1.x;
    r[5] = xc.x * d0.y + xc.y * d1.y;
    r[6] = xc.x * d0.z + xc.y * d1.z;
    r[7] = xc.x * d0.w + xc.y * d1.w;
    #pragma unroll
    for (int off = 1; off < 64; off <<= 1)
        #pragma unroll
        for (int j = 0; j < 8; j++) r[j] += __shfl_xor(r[j], off);
    if (lane == 0) {
        *(float4*)(asrc + node * 4) = make_float4(r[0], r[1], r[2], r[3]);
        *(float4*)(adst + node * 4) = make_float4(r[4], r[5], r[6], r[7]);
    }
}

// ---------------- scatter + per-edge layer1 exps ------------------------------
// p = rowptr[dst] + rank[e]; slot[p] = {src, bf16 attrs}; e1[p] = exp2 of the 4
// leaky'd head alphas (asrc1[s] + adst1[d] + attr.v, all exp2-domain already).
__global__ void k_scatter(const int* __restrict__ ei, const float* __restrict__ eattr,
                          const int* __restrict__ rowptr, const int* __restrict__ rank,
                          const float* __restrict__ asrc, const float* __restrict__ adst,
                          const float* __restrict__ v,
                          int2* __restrict__ slot, float4* __restrict__ e1) {
    int e = blockIdx.x * blockDim.x + threadIdx.x;
    if (e >= EE) return;
    int s = ei[e], d = ei[EE + e];
    int p = rowptr[d] + rank[e];
    float2 a = ((const float2*)eattr)[e];
    unsigned a0 = f2bf(a.x), a1 = f2bf(a.y);
    slot[p] = make_int2(s, (int)(a0 | (a1 << 16)));
    float4 s4 = *(const float4*)(asrc + s * 4);
    float4 d4 = *(const float4*)(adst + d * 4);
    float al0 = s4.x + d4.x + a.x * v[0] + a.y * v[4];
    float al1 = s4.y + d4.y + a.x * v[1] + a.y * v[5];
    float al2 = s4.z + d4.z + a.x * v[2] + a.y * v[6];
    float al3 = s4.w + d4.w + a.x * v[3] + a.y * v[7];
    al0 = (al0 > 0.f) ? al0 : 0.2f * al0;
    al1 = (al1 > 0.f) ? al1 : 0.2f * al1;
    al2 = (al2 > 0.f) ? al2 : 0.2f * al2;
    al3 = (al3 > 0.f) ? al3 : 0.2f * al3;
    float4 ev;
    ev.x = __builtin_amdgcn_exp2f(al0);
    ev.y = __builtin_amdgcn_exp2f(al1);
    ev.z = __builtin_amdgcn_exp2f(al2);
    ev.w = __builtin_amdgcn_exp2f(al3);
    e1[p] = ev;
}

// ---------------- layer1 aggregate of X (weights precomputed) -----------------
// one wave / node; quarter-wave per edge, 4-deep stages + 4-slot ring.
// Ring holds slots one trip ahead -> dependent x-row loads issue with no wait.
// Body: unpack + 16 pk-fma + 4 den adds. No alpha/exp in the loop.
__global__ __launch_bounds__(256) void k_agg1x(const int* __restrict__ rowptr,
                       const int2* __restrict__ slot, const float* __restrict__ e1v,
                       const float* __restrict__ asrc, const float* __restrict__ adst,
                       const float* __restrict__ v,
                       const unsigned short* __restrict__ xb,
                       unsigned short* __restrict__ Sx) {
    int node = blockIdx.x * 4 + (threadIdx.x >> 6);
    if (node >= NN) return;
    int lane = threadIdx.x & 63;
    int q  = lane >> 4;          // edge-in-group (quarter)
    int ql = lane & 15;          // channel-lane: owns ch [ql*8, ql*8+8)
    int beg = rowptr[node], end = rowptr[node + 1];
    int cnt = end - beg;
    int G = cnt >> 2;            // full 4-edge groups
    int safeLast = max(end - 1, 0);
    const unsigned short* xbq = xb + ql * 8;

    f32x2 acc[4][4] = {};        // [head][chan-pair]
    float den[4] = {};
    float s0 = 0.f, s1 = 0.f;

    int2 r0, r1, r2, r3;                 // slot ring
    int at0, at1, at2, at3;              // stage: attrs
    float4 ev0, ev1, ev2, ev3;           // stage: 4-head exps
    uint4 xr0, xr1, xr2, xr3;            // stage: x row

#define A1_LOADR(K, grp) { \
    int _i = min(beg + 4 * (grp) + q, safeLast); \
    r##K = slot[_i]; }
#define A1_LOADX(K, grp) { \
    int _i = min(beg + 4 * (grp) + q, safeLast); \
    at##K = r##K.y; \
    ev##K = *(const float4*)(e1v + (size_t)_i * 4); \
    xr##K = *(const uint4*)(xbq + (size_t)(unsigned)r##K.x * 128); }
#define A1_DO(AT, EV, XR) { \
    f32x2 a = bfpair2((unsigned)(AT)); \
    s0 += a.x; s1 += a.y; \
    den[0] += (EV).x; den[1] += (EV).y; den[2] += (EV).z; den[3] += (EV).w; \
    f32x2 xx[4]; \
    xx[0] = bfpair2((XR).x); xx[1] = bfpair2((XR).y); \
    xx[2] = bfpair2((XR).z); xx[3] = bfpair2((XR).w); \
    f32x2 E0 = {(EV).x, (EV).x}, E1 = {(EV).y, (EV).y}; \
    f32x2 E2 = {(EV).z, (EV).z}, E3 = {(EV).w, (EV).w}; \
    _Pragma("unroll") \
    for (int c = 0; c < 4; c++) { \
        acc[0][c] += E0 * xx[c]; acc[1][c] += E1 * xx[c]; \
        acc[2][c] += E2 * xx[c]; acc[3][c] += E3 * xx[c]; } }
#define A1_BODY(K) A1_DO(at##K, ev##K, xr##K)

    // prologue: ring <- groups 0..3; stages <- groups 0..3; ring <- groups 4..7
    A1_LOADR(0, 0); A1_LOADR(1, 1); A1_LOADR(2, 2); A1_LOADR(3, 3);
    A1_LOADX(0, 0); A1_LOADX(1, 1); A1_LOADX(2, 2); A1_LOADX(3, 3);
    A1_LOADR(0, 4); A1_LOADR(1, 5); A1_LOADR(2, 6); A1_LOADR(3, 7);

    int g = 0;
    #pragma unroll 1
    for (; g + 4 <= G; g += 4) {
        A1_BODY(0); A1_LOADX(0, g + 4); A1_LOADR(0, g + 8);
        A1_BODY(1); A1_LOADX(1, g + 5); A1_LOADR(1, g + 9);
        A1_BODY(2); A1_LOADX(2, g + 6); A1_LOADR(2, g + 10);
        A1_BODY(3); A1_LOADX(3, g + 7); A1_LOADR(3, g + 11);
    }
    if (g     < G) { A1_BODY(0); }
    if (g + 1 < G) { A1_BODY(1); }
    if (g + 2 < G) { A1_BODY(2); }
    if (g + 3 < G) { A1_BODY(3); }

    int tail = cnt & 3;
    if (q < tail) {                      // edges beg+4G+q, q<tail
        int _i = beg + 4 * G + q;
        int2 tl = slot[_i];
        float4 tev = *(const float4*)(e1v + (size_t)_i * 4);
        uint4 txr = *(const uint4*)(xbq + (size_t)(unsigned)tl.x * 128);
        A1_DO(tl.y, tev, txr);
    }
#undef A1_LOADR
#undef A1_LOADX
#undef A1_DO
#undef A1_BODY

    // cross-quarter reductions
    #pragma unroll
    for (int h = 0; h < 4; h++)
        #pragma unroll
        for (int c = 0; c < 4; c++) {
            acc[h][c].x += __shfl_down(acc[h][c].x, 32);
            acc[h][c].y += __shfl_down(acc[h][c].y, 32);
            acc[h][c].x += __shfl_down(acc[h][c].x, 16);
            acc[h][c].y += __shfl_down(acc[h][c].y, 16);
        }
    #pragma unroll
    for (int h = 0; h < 4; h++) {
        den[h] += __shfl_xor(den[h], 16);
        den[h] += __shfl_xor(den[h], 32);
    }
    s0 += __shfl_xor(s0, 16); s0 += __shfl_xor(s0, 32);
    s1 += __shfl_xor(s1, 16); s1 += __shfl_xor(s1, 32);

    // self-loop: mean attrs over real edges (0 if none)
    float dg = fmaxf((float)cnt, 1.0f);
    float m0a = s0 / dg, m1a = s1 / dg;
    float4 an4 = *(const float4*)(asrc + node * 4);
    float4 pd4 = *(const float4*)(adst + node * 4);
    float an[4]  = {an4.x, an4.y, an4.z, an4.w};
    float pdv[4] = {pd4.x, pd4.y, pd4.z, pd4.w};
    float exs[4];
    #pragma unroll
    for (int h = 0; h < 4; h++) {
        float als = an[h] + pdv[h] + m0a * v[h] + m1a * v[4 + h];
        als = (als > 0.f) ? als : 0.2f * als;
        exs[h] = __builtin_amdgcn_exp2f(als);
        den[h] += exs[h];
    }

    if (q == 0) {
        uint4 r = *(const uint4*)(xbq + (size_t)node * 128);
        f32x2 xs[4] = {bfpair2(r.x), bfpair2(r.y), bfpair2(r.z), bfpair2(r.w)};
        #pragma unroll
        for (int h = 0; h < 4; h++) {
            float inv = 1.f / (den[h] + 1e-16f);
            short ov[8];
            #pragma unroll
            for (int c = 0; c < 4; c++) {
                ov[2 * c]     = (short)f2bf((acc[h][c].x + exs[h] * xs[c].x) * inv);
                ov[2 * c + 1] = (short)f2bf((acc[h][c].y + exs[h] * xs[c].y) * inv);
            }
            bf16x8 o8 = {ov[0], ov[1], ov[2], ov[3], ov[4], ov[5], ov[6], ov[7]};
            *(bf16x8*)(Sx + (size_t)node * 512 + h * 128 + ql * 8) = o8;
        }
    }
}

// ---------------- layer1 projection: h2 = ELU(Sx @ W1 (per head) + b1) --------
__global__ __launch_bounds__(256) void k_proj1(const unsigned short* __restrict__ Sx,
                       const unsigned short* __restrict__ W1t,
                       const float* __restrict__ b1,
                       unsigned short* __restrict__ h2b) {
    int h = blockIdx.x;
    int wave = threadIdx.x >> 6, lane = threadIdx.x & 63;
    int l16 = lane & 15, quad = lane >> 4;
    int m0 = blockIdx.y * 128 + wave * 32;

    f32x4 acc[2][4];
    #pragma unroll
    for (int mt = 0; mt < 2; mt++)
        #pragma unroll
        for (int nt = 0; nt < 4; nt++)
            acc[mt][nt] = (f32x4){0.f, 0.f, 0.f, 0.f};

    int ar0 = min(m0 + l16, NN - 1);
    int ar1 = min(m0 + 16 + l16, NN - 1);
    const unsigned short* a0 = Sx + (size_t)ar0 * 512 + h * 128 + quad * 8;
    const unsigned short* a1 = Sx + (size_t)ar1 * 512 + h * 128 + quad * 8;
    const unsigned short* bp = W1t + (size_t)(h * 64 + l16) * 128 + quad * 8;

    #pragma unroll
    for (int k0 = 0; k0 < 128; k0 += 32) {
        bf16x8 af0 = *(const bf16x8*)(a0 + k0);
        bf16x8 af1 = *(const bf16x8*)(a1 + k0);
        #pragma unroll
        for (int nt = 0; nt < 4; nt++) {
            bf16x8 bf = *(const bf16x8*)(bp + (size_t)nt * 16 * 128 + k0);
            acc[0][nt] = __builtin_amdgcn_mfma_f32_16x16x32_bf16(af0, bf, acc[0][nt], 0, 0, 0);
            acc[1][nt] = __builtin_amdgcn_mfma_f32_16x16x32_bf16(af1, bf, acc[1][nt], 0, 0, 0);
        }
    }

    float bia[4];
    #pragma unroll
    for (int nt = 0; nt < 4; nt++) bia[nt] = b1[h * 64 + nt * 16 + l16];

    #pragma unroll
    for (int mt = 0; mt < 2; mt++)
        #pragma unroll
        for (int reg = 0; reg < 4; reg++) {
            int row = m0 + mt * 16 + quad * 4 + reg;
            if (row < NN) {
                #pragma unroll
                for (int nt = 0; nt < 4; nt++) {
                    float va = acc[mt][nt][reg] + bia[nt];
                    va = (va > 0.f) ? va : __expf(va) - 1.f;   // ELU (natural e!)
                    h2b[(size_t)row * 256 + h * 64 + nt * 16 + l16] = f2bf(va);
                }
            }
        }
}

// ---------------- MFMA bf16 GEMM with fused attention-scalar epilogue ---------
// (layer 2 only) asrc/adst outputs scaled by log2e for exp2-domain k_agg2.
template <int K, int NT, int H>
__global__ __launch_bounds__(256) void gemm_mfma(const unsigned short* __restrict__ A,
                                                 const unsigned short* __restrict__ Bt,
                                                 unsigned short* __restrict__ C,
                                                 const float* __restrict__ avs,
                                                 const float* __restrict__ avd,
                                                 float* __restrict__ asrc,
                                                 float* __restrict__ adst,
                                                 int M, int N) {
    int wave = threadIdx.x >> 6, lane = threadIdx.x & 63;
    int l16 = lane & 15, quad = lane >> 4;
    int m0 = blockIdx.y * 128 + wave * 32;
    int n0 = blockIdx.x * (NT * 16);

    f32x4 acc[2][NT];
    #pragma unroll
    for (int mt = 0; mt < 2; mt++)
        #pragma unroll
        for (int nt = 0; nt < NT; nt++)
            acc[mt][nt] = (f32x4){0.f, 0.f, 0.f, 0.f};

    int ar0 = min(m0 + l16, M - 1);
    int ar1 = min(m0 + 16 + l16, M - 1);
    const unsigned short* a0 = A + (size_t)ar0 * K + quad * 8;
    const unsigned short* a1 = A + (size_t)ar1 * K + quad * 8;
    const unsigned short* bp = Bt + (size_t)(n0 + l16) * K + quad * 8;

    #pragma unroll
    for (int k0 = 0; k0 < K; k0 += 32) {
        bf16x8 af0 = *(const bf16x8*)(a0 + k0);
        bf16x8 af1 = *(const bf16x8*)(a1 + k0);
        #pragma unroll
        for (int nt = 0; nt < NT; nt++) {
            bf16x8 bf = *(const bf16x8*)(bp + (size_t)nt * 16 * K + k0);
            acc[0][nt] = __builtin_amdgcn_mfma_f32_16x16x32_bf16(af0, bf, acc[0][nt], 0, 0, 0);
            acc[1][nt] = __builtin_amdgcn_mfma_f32_16x16x32_bf16(af1, bf, acc[1][nt], 0, 0, 0);
        }
    }

    #pragma unroll
    for (int mt = 0; mt < 2; mt++)
        #pragma unroll
        for (int reg = 0; reg < 4; reg++) {
            int row = m0 + mt * 16 + quad * 4 + reg;
            if (row < M) {
                #pragma unroll
                for (int nt = 0; nt < NT; nt++)
                    C[(size_t)row * N + n0 + nt * 16 + l16] = f2bf(acc[mt][nt][reg]);
            }
        }

    float ws[NT], wd[NT];
    #pragma unroll
    for (int nt = 0; nt < NT; nt++) {
        ws[nt] = avs[n0 + nt * 16 + l16] * LOG2E;
        wd[nt] = avd[n0 + nt * 16 + l16] * LOG2E;
    }
    int hh = n0 >> 6;
    #pragma unroll
    for (int mt = 0; mt < 2; mt++)
        #pragma unroll
        for (int reg = 0; reg < 4; reg++) {
            int row = m0 + mt * 16 + quad * 4 + reg;
            float s1 = 0.f, s2 = 0.f;
            #pragma unroll
            for (int nt = 0; nt < NT; nt++) {
                float c = acc[mt][nt][reg];
                s1 += c * ws[nt];
                s2 += c * wd[nt];
            }
            #pragma unroll
            for (int off = 1; off < 16; off <<= 1) {
                s1 += __shfl_xor(s1, off);
                s2 += __shfl_xor(s2, off);
            }
            if (l16 == 0 && row < M) {
                asrc[row * H + hh] = s1;
                adst[row * H + hh] = s2;
            }
        }
}

// ---------------- layer2 fused softmax+aggregate+bias (H=1, 128ch, fp32 out) --
// quarter-wave per edge; same 4-deep stage + 4-slot ring pipeline as agg1x;
// alpha (1 exp) stays in-body.
__global__ __launch_bounds__(256) void k_agg2(const int* __restrict__ rowptr,
                       const int2* __restrict__ slot, const float* __restrict__ asrc,
                       const float* __restrict__ adst, const float* __restrict__ v,
                       const unsigned short* __restrict__ gb, const float* __restrict__ b2,
                       float* __restrict__ outp) {
    int node = blockIdx.x * 4 + (threadIdx.x >> 6);
    if (node >= NN) return;
    int lane = threadIdx.x & 63;
    int q  = lane >> 4;
    int ql = lane & 15;
    int beg = rowptr[node], end = rowptr[node + 1];
    int cnt = end - beg;
    int G = cnt >> 2;
    int safeLast = max(end - 1, 0);
    float ad = adst[node];
    float v0 = v[0], v1 = v[1];
    f32x2 acc[4] = {};
    float den = 0.f, s0 = 0.f, s1 = 0.f;
    const unsigned short* gbq = gb + ql * 8;

    int2 r0, r1, r2, r3;
    int at0, at1, at2, at3;
    float as0, as1_, as2_, as3;
    uint4 xr0, xr1, xr2, xr3;

#define A2_LOADR(K, grp) { \
    int _i = min(beg + 4 * (grp) + q, safeLast); \
    r##K = slot[_i]; }
#define A2_LOADX(K, AS) { \
    at##K = r##K.y; \
    AS = asrc[r##K.x]; \
    xr##K = *(const uint4*)(gbq + (size_t)(unsigned)r##K.x * 128); }
#define A2_DO(AT, AS, XR) { \
    f32x2 a = bfpair2((unsigned)(AT)); \
    float al = (AS) + ad + a.x * v0 + a.y * v1; \
    al = (al > 0.f) ? al : 0.2f * al; \
    float e = __builtin_amdgcn_exp2f(al); \
    s0 += a.x; s1 += a.y; den += e; \
    f32x2 E = {e, e}; \
    acc[0] += E * bfpair2((XR).x); acc[1] += E * bfpair2((XR).y); \
    acc[2] += E * bfpair2((XR).z); acc[3] += E * bfpair2((XR).w); }

    A2_LOADR(0, 0); A2_LOADR(1, 1); A2_LOADR(2, 2); A2_LOADR(3, 3);
    A2_LOADX(0, as0); A2_LOADX(1, as1_); A2_LOADX(2, as2_); A2_LOADX(3, as3);
    A2_LOADR(0, 4); A2_LOADR(1, 5); A2_LOADR(2, 6); A2_LOADR(3, 7);

    int g = 0;
    #pragma unroll 1
    for (; g + 4 <= G; g += 4) {
        A2_DO(at0, as0, xr0);  A2_LOADX(0, as0);  A2_LOADR(0, g + 8);
        A2_DO(at1, as1_, xr1); A2_LOADX(1, as1_); A2_LOADR(1, g + 9);
        A2_DO(at2, as2_, xr2); A2_LOADX(2, as2_); A2_LOADR(2, g + 10);
        A2_DO(at3, as3, xr3);  A2_LOADX(3, as3);  A2_LOADR(3, g + 11);
    }
    if (g     < G) { A2_DO(at0, as0, xr0); }
    if (g + 1 < G) { A2_DO(at1, as1_, xr1); }
    if (g + 2 < G) { A2_DO(at2, as2_, xr2); }
    if (g + 3 < G) { A2_DO(at3, as3, xr3); }

    int tail = cnt & 3;
    if (q < tail) {
        int _i = beg + 4 * G + q;
        int2 tl = slot[_i];
        float tas = asrc[tl.x];
        uint4 txr = *(const uint4*)(gbq + (size_t)(unsigned)tl.x * 128);
        A2_DO(tl.y, tas, txr);
    }
#undef A2_LOADR
#undef A2_LOADX
#undef A2_DO

    #pragma unroll
    for (int k = 0; k < 4; k++) {
        acc[k].x += __shfl_down(acc[k].x, 32);
        acc[k].y += __shfl_down(acc[k].y, 32);
        acc[k].x += __shfl_down(acc[k].x, 16);
        acc[k].y += __shfl_down(acc[k].y, 16);
    }
    den += __shfl_xor(den, 16); den += __shfl_xor(den, 32);
    s0  += __shfl_xor(s0, 16);  s0  += __shfl_xor(s0, 32);
    s1  += __shfl_xor(s1, 16);  s1  += __shfl_xor(s1, 32);

    // self-loop epilogue
    float dg = fmaxf((float)cnt, 1.0f);
    float als = asrc[node] + ad + (s0 / dg) * v0 + (s1 / dg) * v1;
    als = (als > 0.f) ? als : 0.2f * als;
    float exs = __builtin_amdgcn_exp2f(als);
    den += exs;

    if (q == 0) {
        uint4 r = *(const uint4*)(gbq + (size_t)node * 128);
        f32x2 xs0 = bfpair2(r.x), xs1 = bfpair2(r.y);
        f32x2 xs2 = bfpair2(r.z), xs3 = bfpair2(r.w);
        float inv = 1.f / (den + 1e-16f);
        float4 o0, o1;
        o0.x = (acc[0].x + exs * xs0.x) * inv + b2[ql * 8 + 0];
        o0.y = (acc[0].y + exs * xs0.y) * inv + b2[ql * 8 + 1];
        o0.z = (acc[1].x + exs * xs1.x) * inv + b2[ql * 8 + 2];
        o0.w = (acc[1].y + exs * xs1.y) * inv + b2[ql * 8 + 3];
        o1.x = (acc[2].x + exs * xs2.x) * inv + b2[ql * 8 + 4];
        o1.y = (acc[2].y + exs * xs2.y) * inv + b2[ql * 8 + 5];
        o1.z = (acc[3].x + exs * xs3.x) * inv + b2[ql * 8 + 6];
        o1.w = (acc[3].y + exs * xs3.y) * inv + b2[ql * 8 + 7];
        *(float4*)(outp + (size_t)node * 128 + ql * 8)     = o0;
        *(float4*)(outp + (size_t)node * 128 + ql * 8 + 4) = o1;
    }
}

extern "C" void kernel_launch(void* const* d_in, const int* in_sizes, int n_in,
                              void* d_out, int out_size, void* d_ws, size_t ws_size,
                              hipStream_t stream) {
    const float* x     = (const float*)d_in[0];
    const int*   ei    = (const int*)d_in[1];      // int32 on device
    const float* eattr = (const float*)d_in[2];
    const float* W1    = (const float*)d_in[3];
    const float* We1   = (const float*)d_in[4];
    const float* as1   = (const float*)d_in[5];
    const float* ad1   = (const float*)d_in[6];
    const float* ae1   = (const float*)d_in[7];
    const float* b1    = (const float*)d_in[8];
    const float* W2    = (const float*)d_in[9];
    const float* We2   = (const float*)d_in[10];
    const float* as2   = (const float*)d_in[11];
    const float* ad2   = (const float*)d_in[12];
    const float* ae2   = (const float*)d_in[13];
    const float* b2    = (const float*)d_in[14];
    float* out = (float*)d_out;

    // ---- workspace carve ----
    int* idg    = (int*)d_ws;                      // NN
    int* rank   = idg + NN;                        // EE
    int* rowptr = rank + EE;                       // NN+16
    int* bsum   = rowptr + NN + 16;                // 32
    int* boff   = bsum + 32;                       // 32
    int2* slot  = (int2*)(boff + 32);              // EE (8B-aligned)
    float* asrc1 = (float*)(slot + EE);            // 4*NN
    float* adst1 = asrc1 + 4 * NN;                 // 4*NN
    float* asrc2 = adst1 + 4 * NN;                 // NN
    float* adst2 = asrc2 + NN;                     // NN
    float* vbuf  = adst2 + NN;                     // 64
    float* Asd   = vbuf + 64;                      // 1024
    unsigned short* ub = (unsigned short*)(((uintptr_t)(Asd + 1024) + 63) & ~(uintptr_t)63);
    unsigned short* x_bf  = ub;                      // NN*128
    unsigned short* W1t   = x_bf + (size_t)NN * 128; // 256*128
    unsigned short* W2t   = W1t + 32768;             // 128*256
    unsigned short* Sx    = W2t + 32768;             // NN*512
    unsigned short* h2_bf = Sx + (size_t)NN * 512;   // NN*256
    unsigned short* g2_bf = Sx;                      // alias: Sx dead after proj1
    float4* e1   = (float4*)h2_bf;                   // alias: EE*16B = 12.8MB in
                                                     // h2_bf (25.6MB); e1 dead
                                                     // before proj1 writes h2_bf

    hipMemsetAsync(idg, 0, (size_t)NN * sizeof(int), stream);

    // prep (v, Asd, Wt casts, degree hist + rank, x cast) + CSR build
    k_prep<<<9632, 256, 0, stream>>>(We1, ae1, We2, ae2, vbuf, as1, ad1, Asd,
                                     W1, W1t, W2, W2t, ei, idg, rank, x, x_bf);
    k_scan1<<<NB, 512, 0, stream>>>(idg, rowptr, bsum);
    k_scan2<<<1, 64, 0, stream>>>(bsum, boff, rowptr);
    k_scan3<<<NB, 512, 0, stream>>>(rowptr, boff);

    // ---- layer 1 ----  (attn scalars BEFORE scatter; scatter precomputes e1)
    k_attn1<<<(NN + 3) / 4, 256, 0, stream>>>(x_bf, Asd, asrc1, adst1);
    k_scatter<<<(EE + 255) / 256, 256, 0, stream>>>(ei, eattr, rowptr, rank,
                                                    asrc1, adst1, vbuf, slot, e1);
    k_agg1x<<<(NN + 3) / 4, 256, 0, stream>>>(rowptr, slot, (const float*)e1,
                                              asrc1, adst1, vbuf, x_bf, Sx);
    k_proj1<<<dim3(4, (NN + 127) / 128), 256, 0, stream>>>(Sx, W1t, b1, h2_bf);

    // ---- layer 2 ----
    gemm_mfma<256, 8, 1><<<dim3(1, (NN + 127) / 128), 256, 0, stream>>>(
        h2_bf, W2t, g2_bf, as2, ad2, asrc2, adst2, NN, 128);
    k_agg2<<<(NN + 3) / 4, 256, 0, stream>>>(rowptr, slot, asrc2, adst2, vbuf + 8,
                                             g2_bf, b2, out);
}